// Round 1
// baseline (1767.880 us; speedup 1.0000x reference)
//
#include <hip/hip_runtime.h>
#include <hip/hip_bf16.h>

#define N_NODES 8192
#define HID 128
#define OUT_F 64
#define E_EDGES 262144
#define KTOT 192   // OUT_F + HID
#define LDK 104    // padded LDS row stride for 96-element half-K panel

typedef __bf16 bf16x8 __attribute__((ext_vector_type(8)));
typedef float  f32x4  __attribute__((ext_vector_type(4)));

__device__ __forceinline__ unsigned short f2bf(float f) {
    unsigned int u = __float_as_uint(f);
    u += 0x7fffu + ((u >> 16) & 1u);   // RNE
    return (unsigned short)(u >> 16);
}

// ---------------- scatter-add: out[dst[e]] += feat[src[e]], 128 feats/edge ----
__global__ void scatter_add_k(const float* __restrict__ feat,
                              const int* __restrict__ src,
                              const int* __restrict__ dst,
                              float* __restrict__ out) {
    int idx = blockIdx.x * 256 + threadIdx.x;          // E*32 threads
    if (idx >= E_EDGES * 32) return;
    int e = idx >> 5;
    int f = (idx & 31) * 4;
    int s = src[e], d = dst[e];
    float4 v = *(const float4*)(feat + (size_t)s * HID + f);
    float* o = out + (size_t)d * HID + f;
    atomicAdd(o + 0, v.x);
    atomicAdd(o + 1, v.y);
    atomicAdd(o + 2, v.z);
    atomicAdd(o + 3, v.w);
}

// ---------------- h2 = relu(ns1 @ w1 + w1_b), 8192x128 @ 128x128 -------------
__global__ void mlp1_k(const float* __restrict__ ns1,
                       const float* __restrict__ w1,
                       const float* __restrict__ w1b,
                       float* __restrict__ h2) {
    __shared__ float w[HID * HID];   // 64 KB
    int tid = threadIdx.x;
    for (int i = tid; i < HID * HID; i += 256) w[i] = w1[i];
    __syncthreads();
    int c = tid & 127, r0 = tid >> 7;                  // 2 rows per pass
    int rowbase = blockIdx.x * 32;
    for (int rr = r0; rr < 32; rr += 2) {
        int r = rowbase + rr;
        const float4* xr = (const float4*)(ns1 + (size_t)r * HID);
        float acc = w1b[c];
        #pragma unroll
        for (int k4 = 0; k4 < 32; ++k4) {
            float4 v = xr[k4];
            acc += v.x * w[(k4 * 4 + 0) * HID + c];
            acc += v.y * w[(k4 * 4 + 1) * HID + c];
            acc += v.z * w[(k4 * 4 + 2) * HID + c];
            acc += v.w * w[(k4 * 4 + 3) * HID + c];
        }
        h2[(size_t)r * HID + c] = fmaxf(acc, 0.0f);
    }
}

// -------- h = (1-eps)*(x@fc_w+fc_b) + eps*(ns2@w2+w2_b); also emit G bf16 ----
__global__ void fuse_h_k(const float* __restrict__ x,
                         const float* __restrict__ ns2,
                         const float* __restrict__ fcw,
                         const float* __restrict__ fcb,
                         const float* __restrict__ w2,
                         const float* __restrict__ w2b,
                         const float* __restrict__ eps,
                         float* __restrict__ h,
                         unsigned short* __restrict__ G) {
    __shared__ float wA[HID * OUT_F];  // 32 KB
    __shared__ float wB[HID * OUT_F];  // 32 KB
    int tid = threadIdx.x;
    for (int i = tid; i < HID * OUT_F; i += 256) { wA[i] = fcw[i]; wB[i] = w2[i]; }
    __syncthreads();
    int c = tid & 63, r0 = tid >> 6;                   // 4 rows per pass
    int rowbase = blockIdx.x * 32;
    const float SC = 0.70710678f;
    for (int rr = r0; rr < 32; rr += 4) {
        int r = rowbase + rr;
        const float4* xr = (const float4*)(x + (size_t)r * HID);
        const float4* nr = (const float4*)(ns2 + (size_t)r * HID);
        float a1 = fcb[c], a2 = w2b[c];
        #pragma unroll
        for (int k4 = 0; k4 < 32; ++k4) {
            float4 v = xr[k4], u = nr[k4];
            a1 += v.x * wA[(k4 * 4 + 0) * OUT_F + c];
            a1 += v.y * wA[(k4 * 4 + 1) * OUT_F + c];
            a1 += v.z * wA[(k4 * 4 + 2) * OUT_F + c];
            a1 += v.w * wA[(k4 * 4 + 3) * OUT_F + c];
            a2 += u.x * wB[(k4 * 4 + 0) * OUT_F + c];
            a2 += u.y * wB[(k4 * 4 + 1) * OUT_F + c];
            a2 += u.z * wB[(k4 * 4 + 2) * OUT_F + c];
            a2 += u.w * wB[(k4 * 4 + 3) * OUT_F + c];
        }
        float e = eps[r];
        float hv = (1.0f - e) * a1 + e * a2;
        h[(size_t)r * OUT_F + c] = hv;
        unsigned short* Gr = G + (size_t)r * KTOT;
        Gr[c] = f2bf(hv * SC);
        Gr[OUT_F + c]      = f2bf(x[(size_t)r * HID + c] * SC);
        Gr[OUT_F + 64 + c] = f2bf(x[(size_t)r * HID + 64 + c] * SC);
    }
}

// ---------------- BN stats: per-column sum and sumsq over 8192 rows ----------
__global__ void bn_stats_k(const float* __restrict__ h, float* __restrict__ stats) {
    __shared__ float ls[256], lq[256];
    int tid = threadIdx.x;
    int c = tid & 63, r0 = tid >> 6;
    int rowbase = blockIdx.x * 64;
    float s = 0.0f, q = 0.0f;
    for (int rr = r0; rr < 64; rr += 4) {
        float v = h[(size_t)(rowbase + rr) * OUT_F + c];
        s += v; q += v * v;
    }
    ls[tid] = s; lq[tid] = q;
    __syncthreads();
    if (tid < 64) {
        s = ls[tid] + ls[tid + 64] + ls[tid + 128] + ls[tid + 192];
        q = lq[tid] + lq[tid + 64] + lq[tid + 128] + lq[tid + 192];
        atomicAdd(&stats[tid], s);
        atomicAdd(&stats[64 + tid], q);
    }
}

__global__ void bn_apply_k(const float* __restrict__ h,
                           const float* __restrict__ stats,
                           const float* __restrict__ gamma,
                           const float* __restrict__ beta,
                           float* __restrict__ outBN) {
    int idx = blockIdx.x * 256 + threadIdx.x;
    if (idx >= N_NODES * OUT_F) return;
    int c = idx & 63;
    const float inv_n = 1.0f / 8192.0f;
    float m = stats[c] * inv_n;
    float v = stats[64 + c] * inv_n - m * m;
    outBN[idx] = (h[idx] - m) * rsqrtf(v + 1e-5f) * gamma[c] + beta[c];
}

// ---------------- ret = G' @ G'^T  (G' bf16 8192x192, already scaled) --------
__global__ __launch_bounds__(256, 2)
void big_gemm_k(const unsigned short* __restrict__ G, float* __restrict__ C) {
    __shared__ unsigned short Ap[128 * LDK];   // 26 KB
    __shared__ unsigned short Bp[128 * LDK];   // 26 KB
    int tid = threadIdx.x;
    int lane = tid & 63, wid = tid >> 6;
    int wm = wid >> 1, wn = wid & 1;
    int row0 = blockIdx.y * 128, col0 = blockIdx.x * 128;

    f32x4 acc[4][4] = {};

    #pragma unroll
    for (int kh = 0; kh < 2; ++kh) {
        // stage 128 rows x 96 cols (12 uint4 chunks) of each panel
        for (int i = tid; i < 128 * 12; i += 256) {
            int r = i / 12, cc = i % 12;
            *(uint4*)(&Ap[r * LDK + cc * 8]) =
                *(const uint4*)(G + (size_t)(row0 + r) * KTOT + kh * 96 + cc * 8);
            *(uint4*)(&Bp[r * LDK + cc * 8]) =
                *(const uint4*)(G + (size_t)(col0 + r) * KTOT + kh * 96 + cc * 8);
        }
        __syncthreads();
        int rA = wm * 64 + (lane & 15);
        int rB = wn * 64 + (lane & 15);
        int klane = (lane >> 4) * 8;
        #pragma unroll
        for (int ks = 0; ks < 3; ++ks) {
            bf16x8 af[4], bfr[4];
            #pragma unroll
            for (int t = 0; t < 4; ++t) {
                af[t]  = *(const bf16x8*)(&Ap[(rA + t * 16) * LDK + ks * 32 + klane]);
                bfr[t] = *(const bf16x8*)(&Bp[(rB + t * 16) * LDK + ks * 32 + klane]);
            }
            #pragma unroll
            for (int tm = 0; tm < 4; ++tm)
                #pragma unroll
                for (int tn = 0; tn < 4; ++tn)
                    acc[tm][tn] = __builtin_amdgcn_mfma_f32_16x16x32_bf16(
                        af[tm], bfr[tn], acc[tm][tn], 0, 0, 0);
        }
        __syncthreads();
    }

    // epilogue: C/D layout col=lane&15, row=(lane>>4)*4+reg
    int crow = row0 + wm * 64 + (lane >> 4) * 4;
    int ccol = col0 + wn * 64 + (lane & 15);
    #pragma unroll
    for (int tm = 0; tm < 4; ++tm)
        #pragma unroll
        for (int tn = 0; tn < 4; ++tn)
            #pragma unroll
            for (int r = 0; r < 4; ++r)
                C[(size_t)(crow + tm * 16 + r) * N_NODES + (ccol + tn * 16)] =
                    acc[tm][tn][r];
}

extern "C" void kernel_launch(void* const* d_in, const int* in_sizes, int n_in,
                              void* d_out, int out_size, void* d_ws, size_t ws_size,
                              hipStream_t stream) {
    const float* x    = (const float*)d_in[0];
    // d_in[1] = adj (unused by reference)
    const int*   src  = (const int*)d_in[2];
    const int*   dst  = (const int*)d_in[3];
    const float* fcw  = (const float*)d_in[4];
    const float* fcb  = (const float*)d_in[5];
    const float* w1   = (const float*)d_in[6];
    const float* w1b  = (const float*)d_in[7];
    const float* w2   = (const float*)d_in[8];
    const float* w2b  = (const float*)d_in[9];
    const float* eps  = (const float*)d_in[10];
    const float* gamma= (const float*)d_in[11];
    const float* beta = (const float*)d_in[12];

    float* ws = (float*)d_ws;
    float* ns1   = ws;                       // 1048576 f
    float* ns2   = ws + 1048576;             // 1048576 f
    float* h2    = ws + 2097152;             // 1048576 f
    float* h     = ws + 3145728;             //  524288 f
    unsigned short* G = (unsigned short*)(ws + 3670016);   // 8192*192 bf16
    float* stats = ws + 3670016 + 786432;    // 128 f

    float* ret   = (float*)d_out;                    // 8192*8192
    float* outBN = (float*)d_out + (size_t)N_NODES * N_NODES;  // 8192*64

    // zero ns1+ns2 (contiguous 8 MB) and stats
    hipMemsetAsync(ns1, 0, 2 * 1048576 * sizeof(float), stream);
    hipMemsetAsync(stats, 0, 128 * sizeof(float), stream);

    dim3 blk(256);

    // ns1 = segment_sum(x)
    scatter_add_k<<<E_EDGES * 32 / 256, blk, 0, stream>>>(x, src, dst, ns1);
    // h2 = relu(ns1 @ w1 + b)
    mlp1_k<<<N_NODES / 32, blk, 0, stream>>>(ns1, w1, w1b, h2);
    // ns2 = segment_sum(h2)
    scatter_add_k<<<E_EDGES * 32 / 256, blk, 0, stream>>>(h2, src, dst, ns2);
    // h, G
    fuse_h_k<<<N_NODES / 32, blk, 0, stream>>>(x, ns2, fcw, fcb, w2, w2b, eps, h, G);
    // BN
    bn_stats_k<<<N_NODES / 64, blk, 0, stream>>>(h, stats);
    bn_apply_k<<<(N_NODES * OUT_F) / 256, blk, 0, stream>>>(h, stats, gamma, beta, outBN);
    // ret = G'G'^T
    dim3 grid(64, 64);
    big_gemm_k<<<grid, blk, 0, stream>>>(G, ret);
}

// Round 2
// 947.437 us; speedup vs baseline: 1.8660x; 1.8660x over previous
//
#include <hip/hip_runtime.h>
#include <hip/hip_bf16.h>

#define N_NODES 8192
#define HID 128
#define OUT_F 64
#define E_EDGES 262144
#define KTOT 192   // OUT_F + HID
#define LDK 104    // padded LDS row stride for 96-element half-K panel

typedef __bf16 bf16x8 __attribute__((ext_vector_type(8)));
typedef float  f32x4  __attribute__((ext_vector_type(4)));

__device__ __forceinline__ unsigned short f2bf(float f) {
    unsigned int u = __float_as_uint(f);
    u += 0x7fffu + ((u >> 16) & 1u);   // RNE
    return (unsigned short)(u >> 16);
}

// ================= CSR build (incoming edges per node) ======================
__global__ void count_k(const int* __restrict__ dst, int* __restrict__ cnt) {
    int e = blockIdx.x * 256 + threadIdx.x;
    if (e < E_EDGES) atomicAdd(&cnt[dst[e]], 1);
}

// 256 threads, each scans 32 nodes; writes off[0..8192] and cursor copy
__global__ void scan_k(const int* __restrict__ cnt, int* __restrict__ off,
                       int* __restrict__ cursor) {
    __shared__ int part[256];
    int tid = threadIdx.x;
    int base = tid * 32;
    int local[32];
    int s = 0;
    #pragma unroll
    for (int j = 0; j < 32; ++j) { local[j] = s; s += cnt[base + j]; }
    part[tid] = s;
    __syncthreads();
    if (tid == 0) {
        int acc = 0;
        for (int i = 0; i < 256; ++i) { int t = part[i]; part[i] = acc; acc += t; }
    }
    __syncthreads();
    int p = part[tid];
    #pragma unroll
    for (int j = 0; j < 32; ++j) {
        int v = p + local[j];
        off[base + j] = v;
        cursor[base + j] = v;
    }
    if (tid == 255) off[N_NODES] = p + s;
}

__global__ void fill_k(const int* __restrict__ src, const int* __restrict__ dst,
                       int* __restrict__ cursor, int* __restrict__ eidx) {
    int e = blockIdx.x * 256 + threadIdx.x;
    if (e >= E_EDGES) return;
    int pos = atomicAdd(&cursor[dst[e]], 1);
    eidx[pos] = src[e];
}

// ============ gather-sum: out[n] = sum_{j in in-edges(n)} feat[eidx[j]] =====
// one wave per node; lane handles float2 at column lane*2 (512 B coalesced row)
__global__ void gather_sum_k(const float* __restrict__ feat,
                             const int* __restrict__ eidx,
                             const int* __restrict__ off,
                             float* __restrict__ out) {
    int node = blockIdx.x * 4 + (threadIdx.x >> 6);
    int lane = threadIdx.x & 63;
    int beg = off[node], end = off[node + 1];
    float2 a0 = {0.f, 0.f}, a1 = {0.f, 0.f}, a2 = {0.f, 0.f}, a3 = {0.f, 0.f};
    int j = beg;
    for (; j + 4 <= end; j += 4) {
        int s0 = eidx[j], s1 = eidx[j + 1], s2 = eidx[j + 2], s3 = eidx[j + 3];
        float2 v0 = *((const float2*)(feat + (size_t)s0 * HID) + lane);
        float2 v1 = *((const float2*)(feat + (size_t)s1 * HID) + lane);
        float2 v2 = *((const float2*)(feat + (size_t)s2 * HID) + lane);
        float2 v3 = *((const float2*)(feat + (size_t)s3 * HID) + lane);
        a0.x += v0.x; a0.y += v0.y;
        a1.x += v1.x; a1.y += v1.y;
        a2.x += v2.x; a2.y += v2.y;
        a3.x += v3.x; a3.y += v3.y;
    }
    for (; j < end; ++j) {
        int s0 = eidx[j];
        float2 v0 = *((const float2*)(feat + (size_t)s0 * HID) + lane);
        a0.x += v0.x; a0.y += v0.y;
    }
    float2 r;
    r.x = (a0.x + a1.x) + (a2.x + a3.x);
    r.y = (a0.y + a1.y) + (a2.y + a3.y);
    *((float2*)(out + (size_t)node * HID) + lane) = r;
}

// ---------------- h2 = relu(ns1 @ w1 + w1_b), 8192x128 @ 128x128 -------------
__global__ void mlp1_k(const float* __restrict__ ns1,
                       const float* __restrict__ w1,
                       const float* __restrict__ w1b,
                       float* __restrict__ h2) {
    __shared__ float w[HID * HID];   // 64 KB
    int tid = threadIdx.x;
    for (int i = tid; i < HID * HID; i += 256) w[i] = w1[i];
    __syncthreads();
    int c = tid & 127, r0 = tid >> 7;                  // 2 rows per pass
    int rowbase = blockIdx.x * 32;
    for (int rr = r0; rr < 32; rr += 2) {
        int r = rowbase + rr;
        const float4* xr = (const float4*)(ns1 + (size_t)r * HID);
        float acc = w1b[c];
        #pragma unroll
        for (int k4 = 0; k4 < 32; ++k4) {
            float4 v = xr[k4];
            acc += v.x * w[(k4 * 4 + 0) * HID + c];
            acc += v.y * w[(k4 * 4 + 1) * HID + c];
            acc += v.z * w[(k4 * 4 + 2) * HID + c];
            acc += v.w * w[(k4 * 4 + 3) * HID + c];
        }
        h2[(size_t)r * HID + c] = fmaxf(acc, 0.0f);
    }
}

// -------- h = (1-eps)*(x@fc_w+fc_b) + eps*(ns2@w2+w2_b); also emit G bf16 ----
__global__ void fuse_h_k(const float* __restrict__ x,
                         const float* __restrict__ ns2,
                         const float* __restrict__ fcw,
                         const float* __restrict__ fcb,
                         const float* __restrict__ w2,
                         const float* __restrict__ w2b,
                         const float* __restrict__ eps,
                         float* __restrict__ h,
                         unsigned short* __restrict__ G) {
    __shared__ float wA[HID * OUT_F];  // 32 KB
    __shared__ float wB[HID * OUT_F];  // 32 KB
    int tid = threadIdx.x;
    for (int i = tid; i < HID * OUT_F; i += 256) { wA[i] = fcw[i]; wB[i] = w2[i]; }
    __syncthreads();
    int c = tid & 63, r0 = tid >> 6;                   // 4 rows per pass
    int rowbase = blockIdx.x * 32;
    const float SC = 0.70710678f;
    for (int rr = r0; rr < 32; rr += 4) {
        int r = rowbase + rr;
        const float4* xr = (const float4*)(x + (size_t)r * HID);
        const float4* nr = (const float4*)(ns2 + (size_t)r * HID);
        float a1 = fcb[c], a2 = w2b[c];
        #pragma unroll
        for (int k4 = 0; k4 < 32; ++k4) {
            float4 v = xr[k4], u = nr[k4];
            a1 += v.x * wA[(k4 * 4 + 0) * OUT_F + c];
            a1 += v.y * wA[(k4 * 4 + 1) * OUT_F + c];
            a1 += v.z * wA[(k4 * 4 + 2) * OUT_F + c];
            a1 += v.w * wA[(k4 * 4 + 3) * OUT_F + c];
            a2 += u.x * wB[(k4 * 4 + 0) * OUT_F + c];
            a2 += u.y * wB[(k4 * 4 + 1) * OUT_F + c];
            a2 += u.z * wB[(k4 * 4 + 2) * OUT_F + c];
            a2 += u.w * wB[(k4 * 4 + 3) * OUT_F + c];
        }
        float e = eps[r];
        float hv = (1.0f - e) * a1 + e * a2;
        h[(size_t)r * OUT_F + c] = hv;
        unsigned short* Gr = G + (size_t)r * KTOT;
        Gr[c] = f2bf(hv * SC);
        Gr[OUT_F + c]      = f2bf(x[(size_t)r * HID + c] * SC);
        Gr[OUT_F + 64 + c] = f2bf(x[(size_t)r * HID + 64 + c] * SC);
    }
}

// ---------------- BN stats: per-column sum and sumsq over 8192 rows ----------
__global__ void bn_stats_k(const float* __restrict__ h, float* __restrict__ stats) {
    __shared__ float ls[256], lq[256];
    int tid = threadIdx.x;
    int c = tid & 63, r0 = tid >> 6;
    int rowbase = blockIdx.x * 64;
    float s = 0.0f, q = 0.0f;
    for (int rr = r0; rr < 64; rr += 4) {
        float v = h[(size_t)(rowbase + rr) * OUT_F + c];
        s += v; q += v * v;
    }
    ls[tid] = s; lq[tid] = q;
    __syncthreads();
    if (tid < 64) {
        s = ls[tid] + ls[tid + 64] + ls[tid + 128] + ls[tid + 192];
        q = lq[tid] + lq[tid + 64] + lq[tid + 128] + lq[tid + 192];
        atomicAdd(&stats[tid], s);
        atomicAdd(&stats[64 + tid], q);
    }
}

__global__ void bn_apply_k(const float* __restrict__ h,
                           const float* __restrict__ stats,
                           const float* __restrict__ gamma,
                           const float* __restrict__ beta,
                           float* __restrict__ outBN) {
    int idx = blockIdx.x * 256 + threadIdx.x;
    if (idx >= N_NODES * OUT_F) return;
    int c = idx & 63;
    const float inv_n = 1.0f / 8192.0f;
    float m = stats[c] * inv_n;
    float v = stats[64 + c] * inv_n - m * m;
    outBN[idx] = (h[idx] - m) * rsqrtf(v + 1e-5f) * gamma[c] + beta[c];
}

// ---------------- ret = G' @ G'^T  (G' bf16 8192x192, already scaled) --------
__global__ __launch_bounds__(256, 2)
void big_gemm_k(const unsigned short* __restrict__ G, float* __restrict__ C) {
    __shared__ unsigned short Ap[128 * LDK];   // 26 KB
    __shared__ unsigned short Bp[128 * LDK];   // 26 KB
    int tid = threadIdx.x;
    int lane = tid & 63, wid = tid >> 6;
    int wm = wid >> 1, wn = wid & 1;
    int row0 = blockIdx.y * 128, col0 = blockIdx.x * 128;

    f32x4 acc[4][4] = {};

    #pragma unroll
    for (int kh = 0; kh < 2; ++kh) {
        // stage 128 rows x 96 cols (12 uint4 chunks) of each panel
        for (int i = tid; i < 128 * 12; i += 256) {
            int r = i / 12, cc = i % 12;
            *(uint4*)(&Ap[r * LDK + cc * 8]) =
                *(const uint4*)(G + (size_t)(row0 + r) * KTOT + kh * 96 + cc * 8);
            *(uint4*)(&Bp[r * LDK + cc * 8]) =
                *(const uint4*)(G + (size_t)(col0 + r) * KTOT + kh * 96 + cc * 8);
        }
        __syncthreads();
        int rA = wm * 64 + (lane & 15);
        int rB = wn * 64 + (lane & 15);
        int klane = (lane >> 4) * 8;
        #pragma unroll
        for (int ks = 0; ks < 3; ++ks) {
            bf16x8 af[4], bfr[4];
            #pragma unroll
            for (int t = 0; t < 4; ++t) {
                af[t]  = *(const bf16x8*)(&Ap[(rA + t * 16) * LDK + ks * 32 + klane]);
                bfr[t] = *(const bf16x8*)(&Bp[(rB + t * 16) * LDK + ks * 32 + klane]);
            }
            #pragma unroll
            for (int tm = 0; tm < 4; ++tm)
                #pragma unroll
                for (int tn = 0; tn < 4; ++tn)
                    acc[tm][tn] = __builtin_amdgcn_mfma_f32_16x16x32_bf16(
                        af[tm], bfr[tn], acc[tm][tn], 0, 0, 0);
        }
        __syncthreads();
    }

    // epilogue: C/D layout col=lane&15, row=(lane>>4)*4+reg
    int crow = row0 + wm * 64 + (lane >> 4) * 4;
    int ccol = col0 + wn * 64 + (lane & 15);
    #pragma unroll
    for (int tm = 0; tm < 4; ++tm)
        #pragma unroll
        for (int tn = 0; tn < 4; ++tn)
            #pragma unroll
            for (int r = 0; r < 4; ++r)
                C[(size_t)(crow + tm * 16 + r) * N_NODES + (ccol + tn * 16)] =
                    acc[tm][tn][r];
}

extern "C" void kernel_launch(void* const* d_in, const int* in_sizes, int n_in,
                              void* d_out, int out_size, void* d_ws, size_t ws_size,
                              hipStream_t stream) {
    const float* x    = (const float*)d_in[0];
    // d_in[1] = adj (unused by reference)
    const int*   src  = (const int*)d_in[2];
    const int*   dst  = (const int*)d_in[3];
    const float* fcw  = (const float*)d_in[4];
    const float* fcb  = (const float*)d_in[5];
    const float* w1   = (const float*)d_in[6];
    const float* w1b  = (const float*)d_in[7];
    const float* w2   = (const float*)d_in[8];
    const float* w2b  = (const float*)d_in[9];
    const float* eps  = (const float*)d_in[10];
    const float* gamma= (const float*)d_in[11];
    const float* beta = (const float*)d_in[12];

    float* ws = (float*)d_ws;
    float* ns1   = ws;                       // 1048576 f
    float* ns2   = ws + 1048576;             // 1048576 f
    float* h2    = ws + 2097152;             // 1048576 f
    float* h     = ws + 3145728;             //  524288 f
    unsigned short* G = (unsigned short*)(ws + 3670016);   // 8192*192 bf16 = 786432 f
    float* stats = ws + 3670016 + 786432;    // 128 f
    int*   cnt    = (int*)(ws + 3670016 + 786432 + 128);   // 8192 i
    int*   off    = cnt + N_NODES;                          // 8193 i
    int*   cursor = off + N_NODES + 1;                      // 8192 i
    int*   eidx   = cursor + N_NODES;                       // E i

    float* ret   = (float*)d_out;                    // 8192*8192
    float* outBN = (float*)d_out + (size_t)N_NODES * N_NODES;  // 8192*64

    hipMemsetAsync(cnt, 0, N_NODES * sizeof(int), stream);
    hipMemsetAsync(stats, 0, 128 * sizeof(float), stream);

    dim3 blk(256);

    // --- CSR build (shared by both segment_sums) ---
    count_k<<<E_EDGES / 256, blk, 0, stream>>>(dst, cnt);
    scan_k<<<1, blk, 0, stream>>>(cnt, off, cursor);
    fill_k<<<E_EDGES / 256, blk, 0, stream>>>(src, dst, cursor, eidx);

    // ns1 = segment_sum(x)
    gather_sum_k<<<N_NODES / 4, blk, 0, stream>>>(x, eidx, off, ns1);
    // h2 = relu(ns1 @ w1 + b)
    mlp1_k<<<N_NODES / 32, blk, 0, stream>>>(ns1, w1, w1b, h2);
    // ns2 = segment_sum(h2)
    gather_sum_k<<<N_NODES / 4, blk, 0, stream>>>(h2, eidx, off, ns2);
    // h, G
    fuse_h_k<<<N_NODES / 32, blk, 0, stream>>>(x, ns2, fcw, fcb, w2, w2b, eps, h, G);
    // BN
    bn_stats_k<<<N_NODES / 64, blk, 0, stream>>>(h, stats);
    bn_apply_k<<<(N_NODES * OUT_F) / 256, blk, 0, stream>>>(h, stats, gamma, beta, outBN);
    // ret = G'G'^T
    dim3 grid(64, 64);
    big_gemm_k<<<grid, blk, 0, stream>>>(G, ret);
}

// Round 3
// 536.916 us; speedup vs baseline: 3.2927x; 1.7646x over previous
//
#include <hip/hip_runtime.h>
#include <hip/hip_bf16.h>

#define N_NODES 8192
#define HID 128
#define OUT_F 64
#define E_EDGES 262144
#define KTOT 192   // OUT_F + HID
#define LDK 104    // padded LDS row stride for 96-element half-K panel

typedef __bf16 bf16x8 __attribute__((ext_vector_type(8)));
typedef float  f32x4  __attribute__((ext_vector_type(4)));

__device__ __forceinline__ unsigned short f2bf(float f) {
    unsigned int u = __float_as_uint(f);
    u += 0x7fffu + ((u >> 16) & 1u);   // RNE
    return (unsigned short)(u >> 16);
}

// ================= CSR build (incoming edges per node) ======================
__global__ void count_k(const int* __restrict__ dst, int* __restrict__ cnt) {
    int e = blockIdx.x * 256 + threadIdx.x;
    if (e < E_EDGES) atomicAdd(&cnt[dst[e]], 1);
}

// 256 threads, each scans 32 nodes; writes off[0..8192] and cursor copy
__global__ void scan_k(const int* __restrict__ cnt, int* __restrict__ off,
                       int* __restrict__ cursor) {
    __shared__ int part[256];
    int tid = threadIdx.x;
    int base = tid * 32;
    int local[32];
    int s = 0;
    #pragma unroll
    for (int j = 0; j < 32; ++j) { local[j] = s; s += cnt[base + j]; }
    part[tid] = s;
    __syncthreads();
    if (tid == 0) {
        int acc = 0;
        for (int i = 0; i < 256; ++i) { int t = part[i]; part[i] = acc; acc += t; }
    }
    __syncthreads();
    int p = part[tid];
    #pragma unroll
    for (int j = 0; j < 32; ++j) {
        int v = p + local[j];
        off[base + j] = v;
        cursor[base + j] = v;
    }
    if (tid == 255) off[N_NODES] = p + s;
}

__global__ void fill_k(const int* __restrict__ src, const int* __restrict__ dst,
                       int* __restrict__ cursor, int* __restrict__ eidx) {
    int e = blockIdx.x * 256 + threadIdx.x;
    if (e >= E_EDGES) return;
    int pos = atomicAdd(&cursor[dst[e]], 1);
    eidx[pos] = src[e];
}

// ============ gather-sum: out[n] = sum_{j in in-edges(n)} feat[eidx[j]] =====
// one wave per node; lane handles float2 at column lane*2 (512 B coalesced row)
__global__ void gather_sum_k(const float* __restrict__ feat,
                             const int* __restrict__ eidx,
                             const int* __restrict__ off,
                             float* __restrict__ out) {
    int node = blockIdx.x * 4 + (threadIdx.x >> 6);
    int lane = threadIdx.x & 63;
    int beg = off[node], end = off[node + 1];
    float2 a0 = {0.f, 0.f}, a1 = {0.f, 0.f}, a2 = {0.f, 0.f}, a3 = {0.f, 0.f};
    int j = beg;
    for (; j + 4 <= end; j += 4) {
        int s0 = eidx[j], s1 = eidx[j + 1], s2 = eidx[j + 2], s3 = eidx[j + 3];
        float2 v0 = *((const float2*)(feat + (size_t)s0 * HID) + lane);
        float2 v1 = *((const float2*)(feat + (size_t)s1 * HID) + lane);
        float2 v2 = *((const float2*)(feat + (size_t)s2 * HID) + lane);
        float2 v3 = *((const float2*)(feat + (size_t)s3 * HID) + lane);
        a0.x += v0.x; a0.y += v0.y;
        a1.x += v1.x; a1.y += v1.y;
        a2.x += v2.x; a2.y += v2.y;
        a3.x += v3.x; a3.y += v3.y;
    }
    for (; j < end; ++j) {
        int s0 = eidx[j];
        float2 v0 = *((const float2*)(feat + (size_t)s0 * HID) + lane);
        a0.x += v0.x; a0.y += v0.y;
    }
    float2 r;
    r.x = (a0.x + a1.x) + (a2.x + a3.x);
    r.y = (a0.y + a1.y) + (a2.y + a3.y);
    *((float2*)(out + (size_t)node * HID) + lane) = r;
}

// -------- h2 = relu(ns1 @ w1 + w1_b): LDS-staged, K-phased (48 KB LDS) ------
__global__ __launch_bounds__(256)
void mlp1_k(const float* __restrict__ ns1,
            const float* __restrict__ w1,
            const float* __restrict__ w1b,
            float* __restrict__ h2) {
    __shared__ float w[64 * HID];    // 32 KB: one 64-row K-slab of w1
    __shared__ float xs[32 * HID];   // 16 KB: 32 input rows
    int tid = threadIdx.x;
    int rowbase = blockIdx.x * 32;

    // stage x tile: 4096 floats = 1024 float4, coalesced
    for (int i = tid; i < 1024; i += 256)
        *(float4*)&xs[i * 4] = *(const float4*)&ns1[(size_t)rowbase * HID + i * 4];

    int c = tid & 127, r0 = tid >> 7;
    float acc[16];
    #pragma unroll
    for (int g = 0; g < 16; ++g) acc[g] = 0.0f;

    for (int kh = 0; kh < 2; ++kh) {
        __syncthreads();   // covers xs staging (kh=0) and prev-phase reads
        // stage w1 rows [kh*64, kh*64+64): 8192 floats = 2048 float4
        for (int i = tid; i < 2048; i += 256)
            *(float4*)&w[i * 4] = *(const float4*)&w1[(size_t)kh * 8192 + i * 4];
        __syncthreads();
        #pragma unroll
        for (int g = 0; g < 16; ++g) {
            int rr = r0 + g * 2;
            const float* xr = &xs[rr * HID + kh * 64];
            float a = acc[g];
            #pragma unroll 8
            for (int k = 0; k < 64; ++k)
                a += xr[k] * w[k * HID + c];
            acc[g] = a;
        }
    }
    float b = w1b[c];
    #pragma unroll
    for (int g = 0; g < 16; ++g) {
        int rr = r0 + g * 2;
        h2[(size_t)(rowbase + rr) * HID + c] = fmaxf(acc[g] + b, 0.0f);
    }
}

// -------- h = (1-eps)*(x@fc_w+fc_b) + eps*(ns2@w2+w2_b); emit G bf16 --------
// LDS-staged, K-phased (64 KB LDS)
__global__ __launch_bounds__(256)
void fuse_h_k(const float* __restrict__ x,
              const float* __restrict__ ns2,
              const float* __restrict__ fcw,
              const float* __restrict__ fcb,
              const float* __restrict__ w2,
              const float* __restrict__ w2b,
              const float* __restrict__ eps,
              float* __restrict__ h,
              unsigned short* __restrict__ G) {
    __shared__ float wA[64 * OUT_F];  // 16 KB: K-slab of fc_w
    __shared__ float wB[64 * OUT_F];  // 16 KB: K-slab of w2
    __shared__ float xs[32 * HID];    // 16 KB
    __shared__ float nss[32 * HID];   // 16 KB
    int tid = threadIdx.x;
    int rowbase = blockIdx.x * 32;

    for (int i = tid; i < 1024; i += 256) {
        *(float4*)&xs[i * 4]  = *(const float4*)&x[(size_t)rowbase * HID + i * 4];
        *(float4*)&nss[i * 4] = *(const float4*)&ns2[(size_t)rowbase * HID + i * 4];
    }

    int c = tid & 63, r0 = tid >> 6;
    float a1[8], a2[8];
    #pragma unroll
    for (int g = 0; g < 8; ++g) { a1[g] = 0.0f; a2[g] = 0.0f; }

    for (int kh = 0; kh < 2; ++kh) {
        __syncthreads();
        // stage 64-row K-slab of each weight: 4096 floats = 1024 float4 each
        for (int i = tid; i < 1024; i += 256) {
            *(float4*)&wA[i * 4] = *(const float4*)&fcw[(size_t)kh * 4096 + i * 4];
            *(float4*)&wB[i * 4] = *(const float4*)&w2[(size_t)kh * 4096 + i * 4];
        }
        __syncthreads();
        #pragma unroll
        for (int g = 0; g < 8; ++g) {
            int rr = r0 + g * 4;
            const float* xr = &xs[rr * HID + kh * 64];
            const float* nr = &nss[rr * HID + kh * 64];
            float s1 = a1[g], s2 = a2[g];
            #pragma unroll 8
            for (int k = 0; k < 64; ++k) {
                float wa = wA[k * OUT_F + c];
                float wb = wB[k * OUT_F + c];
                s1 += xr[k] * wa;
                s2 += nr[k] * wb;
            }
            a1[g] = s1; a2[g] = s2;
        }
    }

    const float SC = 0.70710678f;
    float b1 = fcb[c], b2 = w2b[c];
    #pragma unroll
    for (int g = 0; g < 8; ++g) {
        int rr = r0 + g * 4;
        int r = rowbase + rr;
        float e = eps[r];
        float hv = (1.0f - e) * (a1[g] + b1) + e * (a2[g] + b2);
        h[(size_t)r * OUT_F + c] = hv;
        unsigned short* Gr = G + (size_t)r * KTOT;
        Gr[c] = f2bf(hv * SC);
        Gr[OUT_F + c]      = f2bf(xs[rr * HID + c] * SC);
        Gr[OUT_F + 64 + c] = f2bf(xs[rr * HID + 64 + c] * SC);
    }
}

// ---------------- BN stats: per-column sum and sumsq over 8192 rows ----------
__global__ void bn_stats_k(const float* __restrict__ h, float* __restrict__ stats) {
    __shared__ float ls[256], lq[256];
    int tid = threadIdx.x;
    int c = tid & 63, r0 = tid >> 6;
    int rowbase = blockIdx.x * 64;
    float s = 0.0f, q = 0.0f;
    for (int rr = r0; rr < 64; rr += 4) {
        float v = h[(size_t)(rowbase + rr) * OUT_F + c];
        s += v; q += v * v;
    }
    ls[tid] = s; lq[tid] = q;
    __syncthreads();
    if (tid < 64) {
        s = ls[tid] + ls[tid + 64] + ls[tid + 128] + ls[tid + 192];
        q = lq[tid] + lq[tid + 64] + lq[tid + 128] + lq[tid + 192];
        atomicAdd(&stats[tid], s);
        atomicAdd(&stats[64 + tid], q);
    }
}

__global__ void bn_apply_k(const float* __restrict__ h,
                           const float* __restrict__ stats,
                           const float* __restrict__ gamma,
                           const float* __restrict__ beta,
                           float* __restrict__ outBN) {
    int idx = blockIdx.x * 256 + threadIdx.x;
    if (idx >= N_NODES * OUT_F) return;
    int c = idx & 63;
    const float inv_n = 1.0f / 8192.0f;
    float m = stats[c] * inv_n;
    float v = stats[64 + c] * inv_n - m * m;
    outBN[idx] = (h[idx] - m) * rsqrtf(v + 1e-5f) * gamma[c] + beta[c];
}

// ---------------- ret = G' @ G'^T  (G' bf16 8192x192, already scaled) --------
__global__ __launch_bounds__(256, 2)
void big_gemm_k(const unsigned short* __restrict__ G, float* __restrict__ C) {
    __shared__ unsigned short Ap[128 * LDK];   // 26 KB
    __shared__ unsigned short Bp[128 * LDK];   // 26 KB
    int tid = threadIdx.x;
    int lane = tid & 63, wid = tid >> 6;
    int wm = wid >> 1, wn = wid & 1;
    int row0 = blockIdx.y * 128, col0 = blockIdx.x * 128;

    f32x4 acc[4][4] = {};

    #pragma unroll
    for (int kh = 0; kh < 2; ++kh) {
        // stage 128 rows x 96 cols (12 uint4 chunks) of each panel
        for (int i = tid; i < 128 * 12; i += 256) {
            int r = i / 12, cc = i % 12;
            *(uint4*)(&Ap[r * LDK + cc * 8]) =
                *(const uint4*)(G + (size_t)(row0 + r) * KTOT + kh * 96 + cc * 8);
            *(uint4*)(&Bp[r * LDK + cc * 8]) =
                *(const uint4*)(G + (size_t)(col0 + r) * KTOT + kh * 96 + cc * 8);
        }
        __syncthreads();
        int rA = wm * 64 + (lane & 15);
        int rB = wn * 64 + (lane & 15);
        int klane = (lane >> 4) * 8;
        #pragma unroll
        for (int ks = 0; ks < 3; ++ks) {
            bf16x8 af[4], bfr[4];
            #pragma unroll
            for (int t = 0; t < 4; ++t) {
                af[t]  = *(const bf16x8*)(&Ap[(rA + t * 16) * LDK + ks * 32 + klane]);
                bfr[t] = *(const bf16x8*)(&Bp[(rB + t * 16) * LDK + ks * 32 + klane]);
            }
            #pragma unroll
            for (int tm = 0; tm < 4; ++tm)
                #pragma unroll
                for (int tn = 0; tn < 4; ++tn)
                    acc[tm][tn] = __builtin_amdgcn_mfma_f32_16x16x32_bf16(
                        af[tm], bfr[tn], acc[tm][tn], 0, 0, 0);
        }
        __syncthreads();
    }

    // epilogue: C/D layout col=lane&15, row=(lane>>4)*4+reg
    int crow = row0 + wm * 64 + (lane >> 4) * 4;
    int ccol = col0 + wn * 64 + (lane & 15);
    #pragma unroll
    for (int tm = 0; tm < 4; ++tm)
        #pragma unroll
        for (int tn = 0; tn < 4; ++tn)
            #pragma unroll
            for (int r = 0; r < 4; ++r)
                C[(size_t)(crow + tm * 16 + r) * N_NODES + (ccol + tn * 16)] =
                    acc[tm][tn][r];
}

extern "C" void kernel_launch(void* const* d_in, const int* in_sizes, int n_in,
                              void* d_out, int out_size, void* d_ws, size_t ws_size,
                              hipStream_t stream) {
    const float* x    = (const float*)d_in[0];
    // d_in[1] = adj (unused by reference)
    const int*   src  = (const int*)d_in[2];
    const int*   dst  = (const int*)d_in[3];
    const float* fcw  = (const float*)d_in[4];
    const float* fcb  = (const float*)d_in[5];
    const float* w1   = (const float*)d_in[6];
    const float* w1b  = (const float*)d_in[7];
    const float* w2   = (const float*)d_in[8];
    const float* w2b  = (const float*)d_in[9];
    const float* eps  = (const float*)d_in[10];
    const float* gamma= (const float*)d_in[11];
    const float* beta = (const float*)d_in[12];

    float* ws = (float*)d_ws;
    float* ns1   = ws;                       // 1048576 f
    float* ns2   = ws + 1048576;             // 1048576 f
    float* h2    = ws + 2097152;             // 1048576 f
    float* h     = ws + 3145728;             //  524288 f
    unsigned short* G = (unsigned short*)(ws + 3670016);   // 8192*192 bf16 = 786432 f
    float* stats = ws + 3670016 + 786432;    // 128 f
    int*   cnt    = (int*)(ws + 3670016 + 786432 + 128);   // 8192 i
    int*   off    = cnt + N_NODES;                          // 8193 i
    int*   cursor = off + N_NODES + 1;                      // 8192 i
    int*   eidx   = cursor + N_NODES;                       // E i

    float* ret   = (float*)d_out;                    // 8192*8192
    float* outBN = (float*)d_out + (size_t)N_NODES * N_NODES;  // 8192*64

    hipMemsetAsync(cnt, 0, N_NODES * sizeof(int), stream);
    hipMemsetAsync(stats, 0, 128 * sizeof(float), stream);

    dim3 blk(256);

    // --- CSR build (shared by both segment_sums) ---
    count_k<<<E_EDGES / 256, blk, 0, stream>>>(dst, cnt);
    scan_k<<<1, blk, 0, stream>>>(cnt, off, cursor);
    fill_k<<<E_EDGES / 256, blk, 0, stream>>>(src, dst, cursor, eidx);

    // ns1 = segment_sum(x)
    gather_sum_k<<<N_NODES / 4, blk, 0, stream>>>(x, eidx, off, ns1);
    // h2 = relu(ns1 @ w1 + b)
    mlp1_k<<<N_NODES / 32, blk, 0, stream>>>(ns1, w1, w1b, h2);
    // ns2 = segment_sum(h2)
    gather_sum_k<<<N_NODES / 4, blk, 0, stream>>>(h2, eidx, off, ns2);
    // h, G
    fuse_h_k<<<N_NODES / 32, blk, 0, stream>>>(x, ns2, fcw, fcb, w2, w2b, eps, h, G);
    // BN
    bn_stats_k<<<N_NODES / 64, blk, 0, stream>>>(h, stats);
    bn_apply_k<<<(N_NODES * OUT_F) / 256, blk, 0, stream>>>(h, stats, gamma, beta, outBN);
    // ret = G'G'^T
    dim3 grid(64, 64);
    big_gemm_k<<<grid, blk, 0, stream>>>(G, ret);
}